// Round 3
// baseline (2102.238 us; speedup 1.0000x reference)
//
#include <hip/hip_runtime.h>
#include <hip/hip_fp16.h>

typedef unsigned short u16;
typedef unsigned int   u32;

#define DIM    64
#define NREL   8
#define NB     4
#define NNODE  150000
#define NEDGE  1000000
#define NSEDGE 200000
#define BATCH  1024
#define SEQL   20
#define NPRED  20
#define TD     384

__device__ __forceinline__ u32 packh2(float lo, float hi) {
    __half2 h;
    h.x = __float2half_rn(lo);
    h.y = __float2half_rn(hi);
    u32 r;
    __builtin_memcpy(&r, &h, 4);
    return r;
}
__device__ __forceinline__ float2 h2pair(u32 w) {
    __half2 h;
    __builtin_memcpy(&h, &w, 4);
    return __half22float2(h);
}

// ---- W[r][d][j] = sum_b comp[r][b]*basis[b][d][j]; packed as (f16 j | f16 j+32) ----
__global__ __launch_bounds__(256) void wpack_kernel(const float* __restrict__ comp,
                                                    const float* __restrict__ basis,
                                                    u32* __restrict__ Wp) {
    int idx = blockIdx.x * 256 + threadIdx.x;     // NREL*64*32 = 16384 total
    int r = idx >> 11;
    int d = (idx >> 5) & 63;
    int jj = idx & 31;
    float c0 = comp[r * NB + 0], c1 = comp[r * NB + 1];
    float c2 = comp[r * NB + 2], c3 = comp[r * NB + 3];
    const float* b0 = basis + 0 * 4096 + d * 64 + jj;
    const float* b1 = basis + 1 * 4096 + d * 64 + jj;
    const float* b2 = basis + 2 * 4096 + d * 64 + jj;
    const float* b3 = basis + 3 * 4096 + d * 64 + jj;
    float lo = c0 * b0[0]  + c1 * b1[0]  + c2 * b2[0]  + c3 * b3[0];
    float hi = c0 * b0[32] + c1 * b1[32] + c2 * b2[32] + c3 * b3[32];
    Wp[idx] = packh2(lo, hi);
}

// ---- root packed the same way: (f16 j | f16 j+32) at [d*32+jj] ----
__global__ __launch_bounds__(256) void rpack_kernel(const float* __restrict__ root,
                                                    u32* __restrict__ Rp) {
    int idx = blockIdx.x * 256 + threadIdx.x;     // 64*32 = 2048 total
    if (idx >= 2048) return;
    int d = idx >> 5, jj = idx & 31;
    Rp[idx] = packh2(root[d * 64 + jj], root[d * 64 + jj + 32]);
}

// ---- per-edge transform + scatter: agg[dst] += x[src] @ W[et] ----
// wave per edge; lane -> (half hf, jj); lane accumulates outputs jj and jj+32 over
// its d-half, halves combined via shfl_xor(32). W in LDS as f16 pairs (64 KB).
__global__ __launch_bounds__(512) void edge_kernel(const float* __restrict__ x,
                                                   const u32* __restrict__ Wp,
                                                   const int* __restrict__ esrc,
                                                   const int* __restrict__ edst,
                                                   const int* __restrict__ etyp,
                                                   float* __restrict__ agg, int E) {
    __shared__ u32 Wl[NREL * 64 * 32];            // 64 KB -> 2 blocks/CU, 16 waves/CU
    for (int i = threadIdx.x; i < NREL * 64 * 32; i += 512) Wl[i] = Wp[i];
    __syncthreads();
    const int lane = threadIdx.x & 63;
    const int hf = lane >> 5;                     // which d-half this lane reduces
    const int jj = lane & 31;
    int wave = blockIdx.x * 8 + (threadIdx.x >> 6);
    const int nw = gridDim.x * 8;
    for (int e = wave; e < E; e += nw) {
        const int s = esrc[e];
        const int dn = edst[e];
        const int r = etyp[e];
        const float* xr = x + (size_t)s * 64 + hf * 32;
        const u32* Wr = &Wl[r * 2048 + hf * 1024 + jj];   // W[r][d=hf*32+dd][jj|jj+32]
        float acc0 = 0.f, acc1 = 0.f;
#pragma unroll
        for (int dd = 0; dd < 32; dd += 4) {
            const float4 xv = *(const float4*)(xr + dd);
            float2 f;
            f = h2pair(Wr[(dd + 0) * 32]); acc0 += xv.x * f.x; acc1 += xv.x * f.y;
            f = h2pair(Wr[(dd + 1) * 32]); acc0 += xv.y * f.x; acc1 += xv.y * f.y;
            f = h2pair(Wr[(dd + 2) * 32]); acc0 += xv.z * f.x; acc1 += xv.z * f.y;
            f = h2pair(Wr[(dd + 3) * 32]); acc0 += xv.w * f.x; acc1 += xv.w * f.y;
        }
        acc0 += __shfl_xor(acc0, 32, 64);         // combine d-halves
        acc1 += __shfl_xor(acc1, 32, 64);
        const float val = hf ? acc1 : acc0;       // hf==0 -> out jj, hf==1 -> out jj+32
        atomicAdd(agg + (size_t)dn * 64 + hf * 32 + jj, val);
    }
}

// ---- x_new = tanh(agg + x @ root + bias), in-place into agg ----
__global__ __launch_bounds__(256) void node_kernel(const float* __restrict__ x,
                                                   float* __restrict__ agg,
                                                   const u32* __restrict__ Rp,
                                                   const float* __restrict__ bias, int N) {
    __shared__ u32 Rl[64 * 32];
    __shared__ float Bl[64];
    for (int i = threadIdx.x; i < 2048; i += 256) Rl[i] = Rp[i];
    if (threadIdx.x < 64) Bl[threadIdx.x] = bias[threadIdx.x];
    __syncthreads();
    const int lane = threadIdx.x & 63;
    const int hf = lane >> 5;
    const int jj = lane & 31;
    int wave = blockIdx.x * 4 + (threadIdx.x >> 6);
    const int nw = gridDim.x * 4;
    for (int n = wave; n < N; n += nw) {
        const float* xr = x + (size_t)n * 64 + hf * 32;
        const u32* Rr = &Rl[hf * 1024 + jj];
        float acc0 = 0.f, acc1 = 0.f;
#pragma unroll
        for (int dd = 0; dd < 32; dd += 4) {
            const float4 xv = *(const float4*)(xr + dd);
            float2 f;
            f = h2pair(Rr[(dd + 0) * 32]); acc0 += xv.x * f.x; acc1 += xv.x * f.y;
            f = h2pair(Rr[(dd + 1) * 32]); acc0 += xv.y * f.x; acc1 += xv.y * f.y;
            f = h2pair(Rr[(dd + 2) * 32]); acc0 += xv.z * f.x; acc1 += xv.z * f.y;
            f = h2pair(Rr[(dd + 3) * 32]); acc0 += xv.w * f.x; acc1 += xv.w * f.y;
        }
        acc0 += __shfl_xor(acc0, 32, 64);
        acc1 += __shfl_xor(acc1, 32, 64);
        const int j = hf * 32 + jj;
        const float v = hf ? acc1 : acc0;
        const size_t o = (size_t)n * 64 + j;
        agg[o] = tanhf(agg[o] + v + Bl[j]);
    }
}

// ---- gather sequence rows -> f32 output column block l ----
__global__ __launch_bounds__(256) void gather_seq_kernel(const float* __restrict__ xc,
                                                         const int* __restrict__ seqs,
                                                         float* __restrict__ out_seq, int l) {
    const int lane = threadIdx.x & 63;
    int wave = blockIdx.x * 4 + (threadIdx.x >> 6);
    const int nw = gridDim.x * 4;
    for (int p = wave; p < BATCH * SEQL; p += nw) {
        const int idx = seqs[p];
        out_seq[(size_t)p * TD + l * 64 + lane] = xc[(size_t)idx * 64 + lane];
    }
}

// ---- per-batch: user row (f32 out) and msum = sum_t seq rows ----
__global__ __launch_bounds__(256) void user_msum_kernel(const float* __restrict__ xc,
                                                        const int* __restrict__ users,
                                                        const int* __restrict__ seqs,
                                                        float* __restrict__ msum,
                                                        float* __restrict__ out_user, int l) {
    const int lane = threadIdx.x & 63;
    int wave = blockIdx.x * 4 + (threadIdx.x >> 6);
    const int nw = gridDim.x * 4;
    for (int b = wave; b < BATCH; b += nw) {
        out_user[(size_t)b * TD + l * 64 + lane] = xc[(size_t)users[b] * 64 + lane];
        float m = 0.f;
        for (int t = 0; t < SEQL; ++t)
            m += xc[(size_t)seqs[b * SEQL + t] * 64 + lane];
        msum[(size_t)b * TD + l * 64 + lane] = m;
    }
}

// ---- final: s = msum @ WV (attention collapsed); res = pw.(user+s) + pb ----
__global__ __launch_bounds__(384) void final_kernel(const float* __restrict__ msum,
                                                    const float* __restrict__ user_f32,
                                                    const float* __restrict__ WV,
                                                    const float* __restrict__ pw,
                                                    const float* __restrict__ pb,
                                                    const int* __restrict__ items,
                                                    float* __restrict__ out_res) {
    __shared__ float ms[TD];
    __shared__ float uL[TD];
    const int b = blockIdx.x;
    const int o = threadIdx.x;
    ms[o] = msum[(size_t)b * TD + o];
    __syncthreads();
    float sv = 0.f;
#pragma unroll 4
    for (int d = 0; d < TD; ++d) sv += ms[d] * WV[d * TD + o];
    uL[o] = user_f32[(size_t)b * TD + o] + sv;
    __syncthreads();
    const int w = threadIdx.x >> 6, lane = threadIdx.x & 63;
    for (int k = w; k < NPRED; k += 6) {
        const int item = items[b * NPRED + k];
        const float* pwr = pw + (size_t)item * TD;
        float a = 0.f;
#pragma unroll
        for (int d = lane; d < TD; d += 64) a += pwr[d] * uL[d];
#pragma unroll
        for (int off = 32; off; off >>= 1) a += __shfl_down(a, off, 64);
        if (lane == 0) out_res[b * NPRED + k] = a + pb[item];
    }
}

extern "C" void kernel_launch(void* const* d_in, const int* in_sizes, int n_in,
                              void* d_out, int out_size, void* d_ws, size_t ws_size,
                              hipStream_t stream) {
    const float* node_emb  = (const float*)d_in[0];
    const float* predict_w = (const float*)d_in[1];
    const float* predict_b = (const float*)d_in[2];
    const float* basis     = (const float*)d_in[3];
    const float* comp      = (const float*)d_in[4];
    const float* root      = (const float*)d_in[5];
    const float* bias      = (const float*)d_in[6];
    const float* sbasis    = (const float*)d_in[7];
    const float* scomp     = (const float*)d_in[8];
    const float* sroot     = (const float*)d_in[9];
    const float* sbias     = (const float*)d_in[10];
    // d_in[11]=WQ, d_in[12]=WK: dead (softmax over summed axis collapses attention)
    const float* WV        = (const float*)d_in[13];
    const int* users       = (const int*)d_in[14];
    const int* seqs        = (const int*)d_in[15];
    const int* items       = (const int*)d_in[16];
    const int* eidx        = (const int*)d_in[17];
    const int* etyp        = (const int*)d_in[18];
    // d_in[19]=node_no: identity gather, dead
    const int* seidx       = (const int*)d_in[20];
    const int* setyp       = (const int*)d_in[21];

    float* xA   = (float*)d_ws;                       // [NNODE*64] f32
    float* xB   = xA + (size_t)NNODE * 64;            // [NNODE*64] f32
    u32*   Wp   = (u32*)(xB + (size_t)NNODE * 64);    // [NREL*64*32] f16 pairs
    u32*   Rp   = Wp + NREL * 64 * 32;                // [64*32] f16 pairs
    float* msum = (float*)(Rp + 64 * 32);             // [BATCH*TD]
    // total ws use ~79 MB

    float* out      = (float*)d_out;                  // reference outputs are float32
    float* out_res  = out;                            // [BATCH*NPRED]
    float* out_user = out + BATCH * NPRED;            // [BATCH*TD]
    float* out_seq  = out_user + (size_t)BATCH * TD;  // [BATCH*SEQL*TD]

    const float* xc = node_emb;   // layer input (layer 0 reads node_emb directly)
    for (int l = 0; l < 6; ++l) {
        const float *bs, *cp, *rt, *bi;
        const int *es, *ed, *et;
        int E;
        if (l < 3) {
            bs = basis  + (size_t)l * NB * DIM * DIM;
            cp = comp   + l * NREL * NB;
            rt = root   + l * DIM * DIM;
            bi = bias   + l * DIM;
            es = eidx; ed = eidx + NEDGE; et = etyp; E = NEDGE;
        } else {
            const int m = l - 3;
            bs = sbasis + (size_t)m * NB * DIM * DIM;
            cp = scomp  + m * NREL * NB;
            rt = sroot  + m * DIM * DIM;
            bi = sbias  + m * DIM;
            es = seidx; ed = seidx + NSEDGE; et = setyp; E = NSEDGE;
        }
        float* xg = (l & 1) ? xB : xA;                    // layer output buffer
        wpack_kernel<<<64, 256, 0, stream>>>(cp, bs, Wp);
        rpack_kernel<<<8, 256, 0, stream>>>(rt, Rp);
        hipMemsetAsync(xg, 0, (size_t)NNODE * DIM * sizeof(float), stream);
        edge_kernel<<<512, 512, 0, stream>>>(xc, Wp, es, ed, et, xg, E);
        node_kernel<<<512, 256, 0, stream>>>(xc, xg, Rp, bi, NNODE);
        gather_seq_kernel<<<320, 256, 0, stream>>>(xg, seqs, out_seq, l);
        user_msum_kernel<<<256, 256, 0, stream>>>(xg, users, seqs, msum, out_user, l);
        xc = xg;
    }

    final_kernel<<<BATCH, 384, 0, stream>>>(msum, out_user, WV, predict_w, predict_b,
                                            items, out_res);
}